// Round 13
// baseline (222.068 us; speedup 1.0000x reference)
//
#include <hip/hip_runtime.h>
#include <stdint.h>

#define D_MODEL 1024
#define T_SEQ   2048
#define BATCH   4
#define NH      16
#define NG      4
#define HD      64

// 0.125 * log2(e): folds softmax scale AND exp->exp2 conversion into Q
#define QSCALE 0.18033688611f

typedef short bf16x8 __attribute__((ext_vector_type(8)));
typedef float f32x4  __attribute__((ext_vector_type(4)));

__device__ __forceinline__ f32x4 mfma16(bf16x8 a, bf16x8 b, f32x4 c) {
    return __builtin_amdgcn_mfma_f32_16x16x32_bf16(a, b, c, 0, 0, 0);
}

// HW bf16 convert (RNE)
__device__ __forceinline__ unsigned short f2bf(float f) {
    __bf16 h = (__bf16)f;
    return __builtin_bit_cast(unsigned short, h);
}

// ---------- cast x (fp32) -> bf16, 4 elems/thread ----------
__global__ void cast_f32_bf16(const float* __restrict__ in,
                              unsigned short* __restrict__ out, int n) {
    int i = (blockIdx.x * blockDim.x + threadIdx.x) * 4;
    if (i < n) {
        float4 v = *reinterpret_cast<const float4*>(in + i);
        ushort4 o;
        o.x = f2bf(v.x); o.y = f2bf(v.y); o.z = f2bf(v.z); o.w = f2bf(v.w);
        *reinterpret_cast<ushort4*>(out + i) = o;
    }
}

// ---------- tiled transpose-cast: in[K][N] fp32 -> out[N][K] bf16 ----------
__global__ __launch_bounds__(256) void transcast(const float* __restrict__ in,
                                                 unsigned short* __restrict__ out,
                                                 int K, int N) {
    __shared__ unsigned short sh[32][33];
    int tx = threadIdx.x & 31, ty = threadIdx.x >> 5;   // 32 x 8
    int n0 = blockIdx.x * 32, k0 = blockIdx.y * 32;
#pragma unroll
    for (int j = 0; j < 4; j++) {
        int k = ty + 8 * j;
        sh[k][tx] = f2bf(in[(size_t)(k0 + k) * N + n0 + tx]);
    }
    __syncthreads();
#pragma unroll
    for (int j = 0; j < 4; j++) {
        int n = ty + 8 * j;
        out[(size_t)(n0 + n) * K + k0 + tx] = sh[tx][n];
    }
}

// ---------- stage one 128x64 bf16 tile: global -> LDS via global_load_lds ----
__device__ __forceinline__ void stage_tile(const unsigned short* __restrict__ src,
                                           unsigned short* lds, int ldK, int tid) {
    int w = tid >> 6;
#pragma unroll
    for (int i = 0; i < 4; i++) {
        int ci  = i * 256 + tid;          // chunk index 0..1023
        int row = ci >> 3, ch = ci & 7;
        int csrc = ch ^ (row & 7);
        const unsigned short* gp = src + (size_t)row * ldK + csrc * 8;
        unsigned short* lp = lds + (size_t)(i * 256 + w * 64) * 8;  // wave-uniform
        __builtin_amdgcn_global_load_lds(
            (const __attribute__((address_space(1))) void*)gp,
            (__attribute__((address_space(3))) void*)lp, 16, 0, 0);
    }
}

// ---------- GEMM m97-style: 128x128 tile, BK=64, 4 waves (2x2) ----------
// MODE 0: fused QKV epilogue (Q scaled by QSCALE; K / Vt scatter layouts).
// MODE 1: fp32 row-major out, bias b0.
template <int MODE>
__global__ __launch_bounds__(256) void gemm128(
        const unsigned short* __restrict__ A,
        const unsigned short* __restrict__ Bt,
        const float* __restrict__ b0, const float* __restrict__ b1,
        const float* __restrict__ b2,
        void* __restrict__ Cq, void* __restrict__ Ck, void* __restrict__ Cv,
        int K) {
    __shared__ unsigned short As[128 * 64];
    __shared__ unsigned short Bs[128 * 64];

    int tid  = threadIdx.x;
    int lane = tid & 63, w = tid >> 6;
    int wr = w >> 1, wc = w & 1;
    int m0 = blockIdx.y * 128, n0 = blockIdx.x * 128;
    int lr = lane & 15, kg = lane >> 4;

    f32x4 acc[4][4] = {};

    const unsigned short* Ab = A  + (size_t)m0 * K;
    const unsigned short* Bb = Bt + (size_t)n0 * K;

    for (int kt = 0; kt < K; kt += 64) {
        stage_tile(Ab + kt, As, K, tid);
        stage_tile(Bb + kt, Bs, K, tid);
        __syncthreads();

        bf16x8 af[4][2], bf[4][2];
#pragma unroll
        for (int mt = 0; mt < 4; mt++) {
            int row = wr * 64 + mt * 16 + lr;
#pragma unroll
            for (int ks = 0; ks < 2; ks++) {
                int ch = (kg + ks * 4) ^ (row & 7);
                af[mt][ks] = *reinterpret_cast<const bf16x8*>(&As[row * 64 + ch * 8]);
            }
        }
#pragma unroll
        for (int nt = 0; nt < 4; nt++) {
            int row = wc * 64 + nt * 16 + lr;
#pragma unroll
            for (int ks = 0; ks < 2; ks++) {
                int ch = (kg + ks * 4) ^ (row & 7);
                bf[nt][ks] = *reinterpret_cast<const bf16x8*>(&Bs[row * 64 + ch * 8]);
            }
        }

#pragma unroll
        for (int ks = 0; ks < 2; ks++)
#pragma unroll
            for (int mt = 0; mt < 4; mt++)
#pragma unroll
                for (int nt = 0; nt < 4; nt++)
                    acc[mt][nt] = mfma16(af[mt][ks], bf[nt][ks], acc[mt][nt]);

        __syncthreads();
    }

    // ---- epilogue ----
    int rbase = kg * 4;
#pragma unroll
    for (int nt = 0; nt < 4; nt++) {
        int col = n0 + wc * 64 + nt * 16 + lr;
        float bias;
        if (MODE == 1)            bias = b0[col];
        else if (col < 1024)      bias = b0[col];
        else if (col < 1280)      bias = b1[col - 1024];
        else                      bias = b2[col - 1280];
#pragma unroll
        for (int mt = 0; mt < 4; mt++) {
#pragma unroll
            for (int r = 0; r < 4; r++) {
                int row = m0 + wr * 64 + mt * 16 + rbase + r;
                float v = acc[mt][nt][r] + bias;
                if (MODE == 1) {
                    ((float*)Cq)[(size_t)row * 1024 + col] = v;
                } else if (col < 1024) {
                    ((unsigned short*)Cq)[(size_t)row * 1024 + col] = f2bf(v * QSCALE);
                } else if (col < 1280) {
                    int cc = col - 1024, g = cc >> 6, d = cc & 63;
                    int b = row >> 11, t = row & 2047;
                    ((unsigned short*)Ck)[(((size_t)(b * NG + g)) * T_SEQ + t) * HD + d] = f2bf(v);
                } else {
                    int cc = col - 1280, g = cc >> 6, d = cc & 63;
                    int b = row >> 11, t = row & 2047;
                    ((unsigned short*)Cv)[(((size_t)(b * NG + g)) * HD + d) * T_SEQ + t] = f2bf(v);
                }
            }
        }
    }
}

// ---------- flash attention v10: 2-wave block, 64 q-rows/wave, den-MFMA ----
// Block = 128 thr = 2 waves; wave w owns q-rows q0 = qt*128 + w*64 (4 x 16).
// Both waves scan ALL key tiles (KVBLK=64); K/V staged in LDS double-buffered
// via global_load_lds (STAGE next || compute current; vmcnt(0)+barrier/tile).
// Per tile the shared kf/vf LDS reads now feed 4 q-tiles = 72 MFMAs/wave.
//
// In-register P (validated v7-v9): swapped QK^T s = mfma(K,Q) gives lane
// (q=lr, grp) keys k=16t+4grp+r; transposed PV O^T = mfma(V^T frag, P frag)
// under kappa(8grp+j)=32kh+16(j>>2)+4grp+(j&3) needs exactly the lane's own
// p values. exp2 (scale pre-folded into Q).
// Denominator via ones-A MFMA: den = mfma(ones, pf) -> every lane's den[0]
// is full sum_k P for its q=lr. No VALU adds, no shfl, no combine.
__global__ __launch_bounds__(128) void attn_fwd(
        const unsigned short* __restrict__ Q,
        const unsigned short* __restrict__ Kt,
        const unsigned short* __restrict__ Vt,
        unsigned short* __restrict__ O) {
    int tid  = threadIdx.x;
    int lane = tid & 63;
    int w    = tid >> 6;
    int qt = blockIdx.x, h = blockIdx.y, b = blockIdx.z;
    int g = h >> 2;                 // HPG = 4
    int lr  = lane & 15;
    int grp = lane >> 4;
    int ko  = grp * 8;
    int q0  = qt * 128 + w * 64;

    __shared__ unsigned short Kl[2][64 * 64];
    __shared__ unsigned short Vl[2][64 * 64];

    const unsigned short* Kp = Kt + ((size_t)(b * NG + g)) * T_SEQ * HD;
    const unsigned short* Vp = Vt + ((size_t)(b * NG + g)) * HD * T_SEQ;

    bf16x8 qf[4][2];
#pragma unroll
    for (int qi = 0; qi < 4; qi++) {
        const unsigned short* Qp =
            Q + ((size_t)(b * T_SEQ + q0 + qi * 16 + lr)) * D_MODEL + h * HD;
        qf[qi][0] = *reinterpret_cast<const bf16x8*>(Qp + ko);
        qf[qi][1] = *reinterpret_cast<const bf16x8*>(Qp + 32 + ko);
    }

    f32x4 oacc[4][4] = {};    // [qi][dt] : O^T, col=q=lr, row=d=dt*16+4grp+reg
    f32x4 den[4] = {};        // ones-MFMA denominator (all rows identical)
    bf16x8 ones;
#pragma unroll
    for (int j = 0; j < 8; j++) ones[j] = (short)0x3F80;   // bf16 1.0

    // ---- stage tile j0 into buffer buf (K: 64 keys x 64 d; V: 64 d x 64 k) ----
    auto STAGE = [&](int buf, int j0) {
#pragma unroll
        for (int i = 0; i < 4; i++) {
            int ci  = i * 128 + tid;          // chunk 0..511
            int row = ci >> 3, ch = ci & 7;
            int csrc = ch ^ (row & 7);
            const unsigned short* gk = Kp + (size_t)(j0 + row) * HD + csrc * 8;
            unsigned short* lk = &Kl[buf][(size_t)(i * 128 + w * 64) * 8];
            __builtin_amdgcn_global_load_lds(
                (const __attribute__((address_space(1))) void*)gk,
                (__attribute__((address_space(3))) void*)lk, 16, 0, 0);
            const unsigned short* gv = Vp + (size_t)row * T_SEQ + j0 + csrc * 8;
            unsigned short* lv = &Vl[buf][(size_t)(i * 128 + w * 64) * 8];
            __builtin_amdgcn_global_load_lds(
                (const __attribute__((address_space(1))) void*)gv,
                (__attribute__((address_space(3))) void*)lv, 16, 0, 0);
        }
    };

    STAGE(0, 0);
    asm volatile("s_waitcnt vmcnt(0)" ::: "memory");
    __syncthreads();

    int cur = 0;
    for (int jt = 0; jt < T_SEQ / 64; jt++) {
        if (jt + 1 < T_SEQ / 64) STAGE(cur ^ 1, (jt + 1) * 64);

        // ---- K fragments from LDS (b128, swizzled) ----
        bf16x8 kf[4][2];
#pragma unroll
        for (int t = 0; t < 4; t++) {
            int row = t * 16 + lr;
#pragma unroll
            for (int ks = 0; ks < 2; ks++) {
                int sch = (ks * 4 + grp) ^ (row & 7);
                kf[t][ks] = *reinterpret_cast<const bf16x8*>(&Kl[cur][row * 64 + sch * 8]);
            }
        }
        // ---- V fragments from LDS, kappa-ordered (2 x b64 each) ----
        bf16x8 vf[4][2];
#pragma unroll
        for (int dt = 0; dt < 4; dt++) {
            int row = dt * 16 + lr, rsw = row & 7;
#pragma unroll
            for (int kh = 0; kh < 2; kh++) {
                int c0 = (kh * 4 + (grp >> 1)) ^ rsw;
                int c2 = (kh * 4 + 2 + (grp >> 1)) ^ rsw;
                short4* halves = reinterpret_cast<short4*>(&vf[dt][kh]);
                halves[0] = *reinterpret_cast<const short4*>(
                    &Vl[cur][row * 64 + c0 * 8 + (grp & 1) * 4]);
                halves[1] = *reinterpret_cast<const short4*>(
                    &Vl[cur][row * 64 + c2 * 8 + (grp & 1) * 4]);
            }
        }

#pragma unroll
        for (int qi = 0; qi < 4; qi++) {
            // ---- S^T = K @ Q (64 keys x 16 q), 8 MFMAs ----
            f32x4 s[4];
            __builtin_amdgcn_s_setprio(1);
#pragma unroll
            for (int t = 0; t < 4; t++) {
                f32x4 a = {};
                a = mfma16(kf[t][0], qf[qi][0], a);
                a = mfma16(kf[t][1], qf[qi][1], a);
                s[t] = a;        // s[t][r] = S[key=16t+4grp+r][q=lr]
            }
            __builtin_amdgcn_s_setprio(0);

            // ---- p = exp2(s) (scale pre-folded into Q) ----
            float p[4][4];
#pragma unroll
            for (int t = 0; t < 4; t++)
#pragma unroll
                for (int r = 0; r < 4; r++)
                    asm("v_exp_f32 %0, %1" : "=v"(p[t][r]) : "v"(s[t][r]));

            // ---- pack P fragments (lane-local, kappa order) ----
            bf16x8 pf0, pf1;
#pragma unroll
            for (int j = 0; j < 4; j++) {
                pf0[j]     = (short)f2bf(p[0][j]);
                pf0[j + 4] = (short)f2bf(p[1][j]);
                pf1[j]     = (short)f2bf(p[2][j]);
                pf1[j + 4] = (short)f2bf(p[3][j]);
            }

            // ---- PV + denominator: 10 MFMAs ----
            __builtin_amdgcn_s_setprio(1);
#pragma unroll
            for (int dt = 0; dt < 4; dt++) {
                oacc[qi][dt] = mfma16(vf[dt][0], pf0, oacc[qi][dt]);
                oacc[qi][dt] = mfma16(vf[dt][1], pf1, oacc[qi][dt]);
            }
            den[qi] = mfma16(ones, pf0, den[qi]);
            den[qi] = mfma16(ones, pf1, den[qi]);
            __builtin_amdgcn_s_setprio(0);
        }

        asm volatile("s_waitcnt vmcnt(0)" ::: "memory");
        __syncthreads();
        cur ^= 1;
    }

    // ---- normalize + write O (den[qi][0] = full row denominator) ----
#pragma unroll
    for (int qi = 0; qi < 4; qi++) {
        float rinv = 1.0f / den[qi][0];
        size_t rowbase = ((size_t)(b * T_SEQ + q0 + qi * 16 + lr)) * D_MODEL + h * HD;
#pragma unroll
        for (int dt = 0; dt < 4; dt++) {
            ushort4 o;
#pragma unroll
            for (int r = 0; r < 4; r++)
                ((unsigned short*)&o)[r] = f2bf(oacc[qi][dt][r] * rinv);
            *reinterpret_cast<ushort4*>(&O[rowbase + dt * 16 + 4 * grp]) = o;
        }
    }
}

extern "C" void kernel_launch(void* const* d_in, const int* in_sizes, int n_in,
                              void* d_out, int out_size, void* d_ws, size_t ws_size,
                              hipStream_t stream) {
    const float* x  = (const float*)d_in[0];
    const float* Wq = (const float*)d_in[1];
    const float* bq = (const float*)d_in[2];
    const float* Wk = (const float*)d_in[3];
    const float* bk = (const float*)d_in[4];
    const float* Wv = (const float*)d_in[5];
    const float* bv = (const float*)d_in[6];
    const float* Wo = (const float*)d_in[7];
    const float* bo = (const float*)d_in[8];

    char* ws = (char*)d_ws;
    // layout (bytes). Wqt|Wkt|Wvt are ADJACENT -> one fused [1536][1024] Bt.
    unsigned short* xb  = (unsigned short*)(ws);             // 16 MB; reused as O
    unsigned short* Wqt = (unsigned short*)(ws + 16777216);  // 2 MB   (rows 0..1023)
    unsigned short* Wkt = (unsigned short*)(ws + 18874368);  // 0.5 MB (rows 1024..1279)
    unsigned short* Wvt = (unsigned short*)(ws + 19398656);  // 0.5 MB (rows 1280..1535)
    unsigned short* Wot = (unsigned short*)(ws + 19922944);  // 2 MB
    unsigned short* Qb  = (unsigned short*)(ws + 22020096);  // 16 MB
    unsigned short* Kb  = (unsigned short*)(ws + 38797312);  // 4 MB
    unsigned short* Vtb = (unsigned short*)(ws + 42991616);  // 4 MB  (total 45 MB)

    const int M = BATCH * T_SEQ;   // 8192

    cast_f32_bf16<<<dim3(M * D_MODEL / 4 / 256), 256, 0, stream>>>(x, xb, M * D_MODEL);
    transcast<<<dim3(32, 32), 256, 0, stream>>>(Wq, Wqt, 1024, 1024);
    transcast<<<dim3(8, 32), 256, 0, stream>>>(Wk, Wkt, 1024, 256);
    transcast<<<dim3(8, 32), 256, 0, stream>>>(Wv, Wvt, 1024, 256);
    transcast<<<dim3(32, 32), 256, 0, stream>>>(Wo, Wot, 1024, 1024);

    // fused QKV projection: [8192][1024] @ [1536][1024]^T
    gemm128<0><<<dim3(12, 64), 256, 0, stream>>>(
        xb, Wqt, bq, bk, bv, Qb, Kb, Vtb, 1024);

    attn_fwd<<<dim3(T_SEQ / 128, NH, BATCH), 128, 0, stream>>>(Qb, Kb, Vtb, xb);

    // output projection -> fp32 d_out
    gemm128<1><<<dim3(8, 64), 256, 0, stream>>>(
        xb, Wot, bo, nullptr, nullptr, d_out, nullptr, nullptr, 1024);
}

// Round 14
// 192.420 us; speedup vs baseline: 1.1541x; 1.1541x over previous
//
#include <hip/hip_runtime.h>
#include <stdint.h>

#define D_MODEL 1024
#define T_SEQ   2048
#define BATCH   4
#define NH      16
#define NG      4
#define HD      64

// 0.125 * log2(e): folds softmax scale AND exp->exp2 conversion into Q
#define QSCALE 0.18033688611f

typedef short bf16x8 __attribute__((ext_vector_type(8)));
typedef float f32x4  __attribute__((ext_vector_type(4)));

__device__ __forceinline__ f32x4 mfma16(bf16x8 a, bf16x8 b, f32x4 c) {
    return __builtin_amdgcn_mfma_f32_16x16x32_bf16(a, b, c, 0, 0, 0);
}

// HW bf16 convert (RNE)
__device__ __forceinline__ unsigned short f2bf(float f) {
    __bf16 h = (__bf16)f;
    return __builtin_bit_cast(unsigned short, h);
}

// ---------- cast x (fp32) -> bf16, 4 elems/thread ----------
__global__ void cast_f32_bf16(const float* __restrict__ in,
                              unsigned short* __restrict__ out, int n) {
    int i = (blockIdx.x * blockDim.x + threadIdx.x) * 4;
    if (i < n) {
        float4 v = *reinterpret_cast<const float4*>(in + i);
        ushort4 o;
        o.x = f2bf(v.x); o.y = f2bf(v.y); o.z = f2bf(v.z); o.w = f2bf(v.w);
        *reinterpret_cast<ushort4*>(out + i) = o;
    }
}

// ---------- tiled transpose-cast: in[K][N] fp32 -> out[N][K] bf16 ----------
__global__ __launch_bounds__(256) void transcast(const float* __restrict__ in,
                                                 unsigned short* __restrict__ out,
                                                 int K, int N) {
    __shared__ unsigned short sh[32][33];
    int tx = threadIdx.x & 31, ty = threadIdx.x >> 5;   // 32 x 8
    int n0 = blockIdx.x * 32, k0 = blockIdx.y * 32;
#pragma unroll
    for (int j = 0; j < 4; j++) {
        int k = ty + 8 * j;
        sh[k][tx] = f2bf(in[(size_t)(k0 + k) * N + n0 + tx]);
    }
    __syncthreads();
#pragma unroll
    for (int j = 0; j < 4; j++) {
        int n = ty + 8 * j;
        out[(size_t)(n0 + n) * K + k0 + tx] = sh[tx][n];
    }
}

// ---------- stage one 128x64 bf16 tile: global -> LDS via global_load_lds ----
__device__ __forceinline__ void stage_tile(const unsigned short* __restrict__ src,
                                           unsigned short* lds, int ldK, int tid) {
    int w = tid >> 6;
#pragma unroll
    for (int i = 0; i < 4; i++) {
        int ci  = i * 256 + tid;          // chunk index 0..1023
        int row = ci >> 3, ch = ci & 7;
        int csrc = ch ^ (row & 7);
        const unsigned short* gp = src + (size_t)row * ldK + csrc * 8;
        unsigned short* lp = lds + (size_t)(i * 256 + w * 64) * 8;  // wave-uniform
        __builtin_amdgcn_global_load_lds(
            (const __attribute__((address_space(1))) void*)gp,
            (__attribute__((address_space(3))) void*)lp, 16, 0, 0);
    }
}

// ---------- GEMM m97-style: 128x128 tile, BK=64, 4 waves (2x2) ----------
// MODE 0: fused QKV epilogue (Q scaled by QSCALE; K / Vt scatter layouts).
// MODE 1: fp32 row-major out, bias b0.
template <int MODE>
__global__ __launch_bounds__(256) void gemm128(
        const unsigned short* __restrict__ A,
        const unsigned short* __restrict__ Bt,
        const float* __restrict__ b0, const float* __restrict__ b1,
        const float* __restrict__ b2,
        void* __restrict__ Cq, void* __restrict__ Ck, void* __restrict__ Cv,
        int K) {
    __shared__ unsigned short As[128 * 64];
    __shared__ unsigned short Bs[128 * 64];

    int tid  = threadIdx.x;
    int lane = tid & 63, w = tid >> 6;
    int wr = w >> 1, wc = w & 1;
    int m0 = blockIdx.y * 128, n0 = blockIdx.x * 128;
    int lr = lane & 15, kg = lane >> 4;

    f32x4 acc[4][4] = {};

    const unsigned short* Ab = A  + (size_t)m0 * K;
    const unsigned short* Bb = Bt + (size_t)n0 * K;

    for (int kt = 0; kt < K; kt += 64) {
        stage_tile(Ab + kt, As, K, tid);
        stage_tile(Bb + kt, Bs, K, tid);
        __syncthreads();

        bf16x8 af[4][2], bf[4][2];
#pragma unroll
        for (int mt = 0; mt < 4; mt++) {
            int row = wr * 64 + mt * 16 + lr;
#pragma unroll
            for (int ks = 0; ks < 2; ks++) {
                int ch = (kg + ks * 4) ^ (row & 7);
                af[mt][ks] = *reinterpret_cast<const bf16x8*>(&As[row * 64 + ch * 8]);
            }
        }
#pragma unroll
        for (int nt = 0; nt < 4; nt++) {
            int row = wc * 64 + nt * 16 + lr;
#pragma unroll
            for (int ks = 0; ks < 2; ks++) {
                int ch = (kg + ks * 4) ^ (row & 7);
                bf[nt][ks] = *reinterpret_cast<const bf16x8*>(&Bs[row * 64 + ch * 8]);
            }
        }

#pragma unroll
        for (int ks = 0; ks < 2; ks++)
#pragma unroll
            for (int mt = 0; mt < 4; mt++)
#pragma unroll
                for (int nt = 0; nt < 4; nt++)
                    acc[mt][nt] = mfma16(af[mt][ks], bf[nt][ks], acc[mt][nt]);

        __syncthreads();
    }

    // ---- epilogue ----
    int rbase = kg * 4;
#pragma unroll
    for (int nt = 0; nt < 4; nt++) {
        int col = n0 + wc * 64 + nt * 16 + lr;
        float bias;
        if (MODE == 1)            bias = b0[col];
        else if (col < 1024)      bias = b0[col];
        else if (col < 1280)      bias = b1[col - 1024];
        else                      bias = b2[col - 1280];
#pragma unroll
        for (int mt = 0; mt < 4; mt++) {
#pragma unroll
            for (int r = 0; r < 4; r++) {
                int row = m0 + wr * 64 + mt * 16 + rbase + r;
                float v = acc[mt][nt][r] + bias;
                if (MODE == 1) {
                    ((float*)Cq)[(size_t)row * 1024 + col] = v;
                } else if (col < 1024) {
                    ((unsigned short*)Cq)[(size_t)row * 1024 + col] = f2bf(v * QSCALE);
                } else if (col < 1280) {
                    int cc = col - 1024, g = cc >> 6, d = cc & 63;
                    int b = row >> 11, t = row & 2047;
                    ((unsigned short*)Ck)[(((size_t)(b * NG + g)) * T_SEQ + t) * HD + d] = f2bf(v);
                } else {
                    int cc = col - 1280, g = cc >> 6, d = cc & 63;
                    int b = row >> 11, t = row & 2047;
                    ((unsigned short*)Cv)[(((size_t)(b * NG + g)) * HD + d) * T_SEQ + t] = f2bf(v);
                }
            }
        }
    }
}

// ---------- flash attention v11: v9 structure + ones-MFMA denominator ----------
// Block = 256 thr = 4 waves; wave w owns q-rows q0 = qt*128 + w*32 (2 x 16).
// All waves scan ALL key tiles (KVBLK=64) together; K and V tiles staged in
// LDS via global_load_lds (double-buffered: STAGE next || compute current,
// one vmcnt(0)+barrier per tile). 4x load amortization across waves.
// LDS tiles chunk-XOR swizzled (rule #21); readers XOR identically.
//
// In-register P (validated v7-v10): swapped QK^T s = mfma(K,Q) gives lane
// (q=lr, grp) keys k=16t+4grp+r; transposed PV O^T = mfma(V^T frag, P frag)
// under kappa(8grp+j)=32kh+16(j>>2)+4grp+(j&3) needs exactly the lane's own
// p values. exp2 (scale pre-folded into Q).
// Denominator via ones-A MFMA (validated v10): den = mfma(ones, pf) ->
// every lane's den[0] = full sum_k P for its q=lr. No VALU adds, no shfl.
// VGPR budget: ~104 (must stay <=128 -- v10 lesson: 136 VGPR halved occupancy).
__global__ __launch_bounds__(256) void attn_fwd(
        const unsigned short* __restrict__ Q,
        const unsigned short* __restrict__ Kt,
        const unsigned short* __restrict__ Vt,
        unsigned short* __restrict__ O) {
    int tid  = threadIdx.x;
    int lane = tid & 63;
    int w    = tid >> 6;
    int qt = blockIdx.x, h = blockIdx.y, b = blockIdx.z;
    int g = h >> 2;                 // HPG = 4
    int lr  = lane & 15;
    int grp = lane >> 4;
    int ko  = grp * 8;
    int q0  = qt * 128 + w * 32;

    __shared__ unsigned short Kl[2][64 * 64];
    __shared__ unsigned short Vl[2][64 * 64];

    const unsigned short* Kp = Kt + ((size_t)(b * NG + g)) * T_SEQ * HD;
    const unsigned short* Vp = Vt + ((size_t)(b * NG + g)) * HD * T_SEQ;

    bf16x8 qf[2][2];
#pragma unroll
    for (int qi = 0; qi < 2; qi++) {
        const unsigned short* Qp =
            Q + ((size_t)(b * T_SEQ + q0 + qi * 16 + lr)) * D_MODEL + h * HD;
        qf[qi][0] = *reinterpret_cast<const bf16x8*>(Qp + ko);
        qf[qi][1] = *reinterpret_cast<const bf16x8*>(Qp + 32 + ko);
    }

    f32x4 oacc[2][4] = {};    // [qi][dt] : O^T, col=q=lr, row=d=dt*16+4grp+reg
    f32x4 den[2] = {};        // ones-MFMA denominator (all rows identical)
    bf16x8 ones;
#pragma unroll
    for (int j = 0; j < 8; j++) ones[j] = (short)0x3F80;   // bf16 1.0

    // ---- stage tile j0 into buffer buf (K: 64 keys x 64 d; V: 64 d x 64 k) ----
    auto STAGE = [&](int buf, int j0) {
#pragma unroll
        for (int i = 0; i < 2; i++) {
            int ci  = i * 256 + tid;          // chunk 0..511
            int row = ci >> 3, ch = ci & 7;
            int csrc = ch ^ (row & 7);
            const unsigned short* gk = Kp + (size_t)(j0 + row) * HD + csrc * 8;
            unsigned short* lk = &Kl[buf][(size_t)(i * 256 + w * 64) * 8];
            __builtin_amdgcn_global_load_lds(
                (const __attribute__((address_space(1))) void*)gk,
                (__attribute__((address_space(3))) void*)lk, 16, 0, 0);
            const unsigned short* gv = Vp + (size_t)row * T_SEQ + j0 + csrc * 8;
            unsigned short* lv = &Vl[buf][(size_t)(i * 256 + w * 64) * 8];
            __builtin_amdgcn_global_load_lds(
                (const __attribute__((address_space(1))) void*)gv,
                (__attribute__((address_space(3))) void*)lv, 16, 0, 0);
        }
    };

    STAGE(0, 0);
    asm volatile("s_waitcnt vmcnt(0)" ::: "memory");
    __syncthreads();

    int cur = 0;
    for (int jt = 0; jt < T_SEQ / 64; jt++) {
        if (jt + 1 < T_SEQ / 64) STAGE(cur ^ 1, (jt + 1) * 64);

        // ---- K fragments from LDS (b128, swizzled) ----
        bf16x8 kf[4][2];
#pragma unroll
        for (int t = 0; t < 4; t++) {
            int row = t * 16 + lr;
#pragma unroll
            for (int ks = 0; ks < 2; ks++) {
                int sch = (ks * 4 + grp) ^ (row & 7);
                kf[t][ks] = *reinterpret_cast<const bf16x8*>(&Kl[cur][row * 64 + sch * 8]);
            }
        }
        // ---- V fragments from LDS, kappa-ordered (2 x b64 each) ----
        bf16x8 vf[4][2];
#pragma unroll
        for (int dt = 0; dt < 4; dt++) {
            int row = dt * 16 + lr, rsw = row & 7;
#pragma unroll
            for (int kh = 0; kh < 2; kh++) {
                int c0 = (kh * 4 + (grp >> 1)) ^ rsw;
                int c2 = (kh * 4 + 2 + (grp >> 1)) ^ rsw;
                short4* halves = reinterpret_cast<short4*>(&vf[dt][kh]);
                halves[0] = *reinterpret_cast<const short4*>(
                    &Vl[cur][row * 64 + c0 * 8 + (grp & 1) * 4]);
                halves[1] = *reinterpret_cast<const short4*>(
                    &Vl[cur][row * 64 + c2 * 8 + (grp & 1) * 4]);
            }
        }

#pragma unroll
        for (int qi = 0; qi < 2; qi++) {
            // ---- S^T = K @ Q (64 keys x 16 q), 8 MFMAs ----
            f32x4 s[4];
            __builtin_amdgcn_s_setprio(1);
#pragma unroll
            for (int t = 0; t < 4; t++) {
                f32x4 a = {};
                a = mfma16(kf[t][0], qf[qi][0], a);
                a = mfma16(kf[t][1], qf[qi][1], a);
                s[t] = a;        // s[t][r] = S[key=16t+4grp+r][q=lr]
            }
            __builtin_amdgcn_s_setprio(0);

            // ---- p = exp2(s) (scale pre-folded into Q) ----
            float p[4][4];
#pragma unroll
            for (int t = 0; t < 4; t++)
#pragma unroll
                for (int r = 0; r < 4; r++)
                    asm("v_exp_f32 %0, %1" : "=v"(p[t][r]) : "v"(s[t][r]));

            // ---- pack P fragments (lane-local, kappa order) ----
            bf16x8 pf0, pf1;
#pragma unroll
            for (int j = 0; j < 4; j++) {
                pf0[j]     = (short)f2bf(p[0][j]);
                pf0[j + 4] = (short)f2bf(p[1][j]);
                pf1[j]     = (short)f2bf(p[2][j]);
                pf1[j + 4] = (short)f2bf(p[3][j]);
            }

            // ---- PV + ones-denominator: 10 MFMAs ----
            __builtin_amdgcn_s_setprio(1);
#pragma unroll
            for (int dt = 0; dt < 4; dt++) {
                oacc[qi][dt] = mfma16(vf[dt][0], pf0, oacc[qi][dt]);
                oacc[qi][dt] = mfma16(vf[dt][1], pf1, oacc[qi][dt]);
            }
            den[qi] = mfma16(ones, pf0, den[qi]);
            den[qi] = mfma16(ones, pf1, den[qi]);
            __builtin_amdgcn_s_setprio(0);
        }

        asm volatile("s_waitcnt vmcnt(0)" ::: "memory");
        __syncthreads();
        cur ^= 1;
    }

    // ---- normalize + write O (den[qi][0] = full row denominator) ----
#pragma unroll
    for (int qi = 0; qi < 2; qi++) {
        float rinv = 1.0f / den[qi][0];
        size_t rowbase = ((size_t)(b * T_SEQ + q0 + qi * 16 + lr)) * D_MODEL + h * HD;
#pragma unroll
        for (int dt = 0; dt < 4; dt++) {
            ushort4 o;
#pragma unroll
            for (int r = 0; r < 4; r++)
                ((unsigned short*)&o)[r] = f2bf(oacc[qi][dt][r] * rinv);
            *reinterpret_cast<ushort4*>(&O[rowbase + dt * 16 + 4 * grp]) = o;
        }
    }
}

extern "C" void kernel_launch(void* const* d_in, const int* in_sizes, int n_in,
                              void* d_out, int out_size, void* d_ws, size_t ws_size,
                              hipStream_t stream) {
    const float* x  = (const float*)d_in[0];
    const float* Wq = (const float*)d_in[1];
    const float* bq = (const float*)d_in[2];
    const float* Wk = (const float*)d_in[3];
    const float* bk = (const float*)d_in[4];
    const float* Wv = (const float*)d_in[5];
    const float* bv = (const float*)d_in[6];
    const float* Wo = (const float*)d_in[7];
    const float* bo = (const float*)d_in[8];

    char* ws = (char*)d_ws;
    // layout (bytes). Wqt|Wkt|Wvt are ADJACENT -> one fused [1536][1024] Bt.
    unsigned short* xb  = (unsigned short*)(ws);             // 16 MB; reused as O
    unsigned short* Wqt = (unsigned short*)(ws + 16777216);  // 2 MB   (rows 0..1023)
    unsigned short* Wkt = (unsigned short*)(ws + 18874368);  // 0.5 MB (rows 1024..1279)
    unsigned short* Wvt = (unsigned short*)(ws + 19398656);  // 0.5 MB (rows 1280..1535)
    unsigned short* Wot = (unsigned short*)(ws + 19922944);  // 2 MB
    unsigned short* Qb  = (unsigned short*)(ws + 22020096);  // 16 MB
    unsigned short* Kb  = (unsigned short*)(ws + 38797312);  // 4 MB
    unsigned short* Vtb = (unsigned short*)(ws + 42991616);  // 4 MB  (total 45 MB)

    const int M = BATCH * T_SEQ;   // 8192

    cast_f32_bf16<<<dim3(M * D_MODEL / 4 / 256), 256, 0, stream>>>(x, xb, M * D_MODEL);
    transcast<<<dim3(32, 32), 256, 0, stream>>>(Wq, Wqt, 1024, 1024);
    transcast<<<dim3(8, 32), 256, 0, stream>>>(Wk, Wkt, 1024, 256);
    transcast<<<dim3(8, 32), 256, 0, stream>>>(Wv, Wvt, 1024, 256);
    transcast<<<dim3(32, 32), 256, 0, stream>>>(Wo, Wot, 1024, 1024);

    // fused QKV projection: [8192][1024] @ [1536][1024]^T
    gemm128<0><<<dim3(12, 64), 256, 0, stream>>>(
        xb, Wqt, bq, bk, bv, Qb, Kb, Vtb, 1024);

    attn_fwd<<<dim3(T_SEQ / 128, NH, BATCH), 256, 0, stream>>>(Qb, Kb, Vtb, xb);

    // output projection -> fp32 d_out
    gemm128<1><<<dim3(8, 64), 256, 0, stream>>>(
        xb, Wot, bo, nullptr, nullptr, d_out, nullptr, nullptr, 1024);
}